// Round 3
// baseline (218.558 us; speedup 1.0000x reference)
//
#include <hip/hip_runtime.h>
#include <cstdint>

// CrossLayerAttention on MI355X (gfx950).  B=4 S=1024 H=2048 NH=16 HD=128.
// R3: barrier-free per-wave flash attention (direct-L2 K/V frag reads, paired
//     causal q-tiles, wave-private P); RoPE fused into Q-proj GEMM epilogue.

typedef unsigned short u16;
typedef __bf16 bf16x8 __attribute__((ext_vector_type(8)));
typedef float  f32x4  __attribute__((ext_vector_type(4)));

__device__ __forceinline__ u16 f2bf(float f) {
  uint32_t u = __builtin_bit_cast(uint32_t, f);
  u += 0x7fffu + ((u >> 16) & 1u);   // RNE; inputs finite
  return (u16)(u >> 16);
}
__device__ __forceinline__ float bf2f(u16 h) {
  uint32_t u = ((uint32_t)h) << 16;
  return __builtin_bit_cast(float, u);
}
__device__ __forceinline__ void gld16(const void* g, void* l) {
  __builtin_amdgcn_global_load_lds(
      (const __attribute__((address_space(1))) void*)g,
      (__attribute__((address_space(3))) void*)l, 16, 0, 0);
}

// ---------------- fp32 -> bf16 convert ----------------
__global__ __launch_bounds__(256) void cvt_kernel(const float* __restrict__ in,
                                                  u16* __restrict__ out, int n4) {
  int i = blockIdx.x * 256 + threadIdx.x;
  if (i < n4) {
    float4 v = ((const float4*)in)[i];
    ushort4 o;
    o.x = f2bf(v.x); o.y = f2bf(v.y); o.z = f2bf(v.z); o.w = f2bf(v.w);
    ((ushort4*)out)[i] = o;
  }
}

// ---------------- per-bh transpose + cvt: out[c][r] = bf16(in[r][c]) ----------------
__global__ __launch_bounds__(256) void transpose_cvt(const float* __restrict__ in,
                                                     u16* __restrict__ out, int R, int C) {
  __shared__ float tile[32][33];
  const int bh = blockIdx.x;
  const int nct = C >> 5;
  const int rt = blockIdx.y / nct, ct = blockIdx.y % nct;
  const float* src = in + (size_t)bh * R * C;
  u16* dst = out + (size_t)bh * R * C;
  const int r = threadIdx.x >> 3, c4 = (threadIdx.x & 7) * 4;
  float4 v = *(const float4*)(src + (size_t)(rt * 32 + r) * C + ct * 32 + c4);
  tile[r][c4 + 0] = v.x; tile[r][c4 + 1] = v.y;
  tile[r][c4 + 2] = v.z; tile[r][c4 + 3] = v.w;
  __syncthreads();
  ushort4 o;
  o.x = f2bf(tile[c4 + 0][r]); o.y = f2bf(tile[c4 + 1][r]);
  o.z = f2bf(tile[c4 + 2][r]); o.w = f2bf(tile[c4 + 3][r]);
  *(ushort4*)(dst + (size_t)(ct * 32 + r) * R + rt * 32 + c4) = o;
}

// ---------------- GEMM (out-proj): C[M,N] = A[M,K] @ B[N,K]^T + bias ----------------
// 128x128 tile, BK=32, 4 waves 2x2, global_load_lds width-16 staging (m97).
template<bool OUT_BF16>
__global__ __launch_bounds__(256, 2)
void gemm_bt(const u16* __restrict__ A, const u16* __restrict__ Bm,
             const float* __restrict__ bias, void* __restrict__ Cout,
             int M, int N, int K) {
  __shared__ __align__(16) u16 As[128 * 32];
  __shared__ __align__(16) u16 Bs[128 * 32];
  const int t = threadIdx.x, lane = t & 63, w = t >> 6;
  const int row0 = blockIdx.x * 128, col0 = blockIdx.y * 128;
  const int wr = (w >> 1) * 64, wc = (w & 1) * 64;
  const int fr = lane & 15, fg = lane >> 4, fk = fg * 8;
  const int srow = w * 32 + (lane >> 2), scol = (lane & 3) * 8;
  const u16* gA0 = A  + (size_t)(row0 + srow) * K + scol;
  const u16* gB0 = Bm + (size_t)(col0 + srow) * K + scol;
  u16* lA0 = As + (w * 32) * 32;
  u16* lA1 = As + (w * 32 + 16) * 32;
  u16* lB0 = Bs + (w * 32) * 32;
  u16* lB1 = Bs + (w * 32 + 16) * 32;
  f32x4 acc[4][4] = {};

  for (int k0 = 0; k0 < K; k0 += 32) {
    __syncthreads();
    gld16(gA0 + k0, lA0);
    gld16(gA0 + k0 + (size_t)16 * K, lA1);
    gld16(gB0 + k0, lB0);
    gld16(gB0 + k0 + (size_t)16 * K, lB1);
    __syncthreads();
    bf16x8 af[4], bq[4];
#pragma unroll
    for (int i = 0; i < 4; i++) af[i] = *(const bf16x8*)&As[(wr + i * 16 + fr) * 32 + fk];
#pragma unroll
    for (int i = 0; i < 4; i++) bq[i] = *(const bf16x8*)&Bs[(wc + i * 16 + fr) * 32 + fk];
#pragma unroll
    for (int mi = 0; mi < 4; mi++)
#pragma unroll
      for (int ni = 0; ni < 4; ni++)
        acc[mi][ni] = __builtin_amdgcn_mfma_f32_16x16x32_bf16(af[mi], bq[ni], acc[mi][ni], 0, 0, 0);
  }

#pragma unroll
  for (int mi = 0; mi < 4; mi++)
#pragma unroll
    for (int ni = 0; ni < 4; ni++) {
      int col = col0 + wc + ni * 16 + fr;
      float bv = bias[col];
#pragma unroll
      for (int i = 0; i < 4; i++) {
        int row = row0 + wr + mi * 16 + fg * 4 + i;
        float v = acc[mi][ni][i] + bv;
        if constexpr (OUT_BF16) ((u16*)Cout)[(size_t)row * N + col] = f2bf(v);
        else                    ((float*)Cout)[(size_t)row * N + col] = v;
      }
    }
}

// ---------------- Q-proj GEMM with fused RoPE epilogue ----------------
// Wave tiling 4x1: wave owns 32 rows x 128 cols (one full head width) so the
// rope pair (d, d+64) lives in frags ni and ni+4. Writes q_bf[bh][s][d] directly.
__global__ __launch_bounds__(256, 2)
void gemm_rope(const u16* __restrict__ A, const u16* __restrict__ Bm,
               const float* __restrict__ bias, const float* __restrict__ cosb,
               const float* __restrict__ sinb, u16* __restrict__ qout) {
  __shared__ __align__(16) u16 As[128 * 32];
  __shared__ __align__(16) u16 Bs[128 * 32];
  const int K = 2048;
  const int t = threadIdx.x, lane = t & 63, w = t >> 6;
  const int row0 = blockIdx.x * 128, h = blockIdx.y;
  const int wr = w * 32;
  const int fr = lane & 15, fg = lane >> 4, fk = fg * 8;
  const int srow = w * 32 + (lane >> 2), scol = (lane & 3) * 8;
  const u16* gA0 = A  + (size_t)(row0 + srow) * K + scol;
  const u16* gB0 = Bm + (size_t)(h * 128 + srow) * K + scol;
  u16* lA0 = As + (w * 32) * 32;
  u16* lA1 = As + (w * 32 + 16) * 32;
  u16* lB0 = Bs + (w * 32) * 32;
  u16* lB1 = Bs + (w * 32 + 16) * 32;
  f32x4 acc[2][8] = {};

  for (int k0 = 0; k0 < K; k0 += 32) {
    __syncthreads();
    gld16(gA0 + k0, lA0);
    gld16(gA0 + k0 + (size_t)16 * K, lA1);
    gld16(gB0 + k0, lB0);
    gld16(gB0 + k0 + (size_t)16 * K, lB1);
    __syncthreads();
    bf16x8 af[2], bq[8];
#pragma unroll
    for (int mi = 0; mi < 2; mi++) af[mi] = *(const bf16x8*)&As[(wr + mi * 16 + fr) * 32 + fk];
#pragma unroll
    for (int ni = 0; ni < 8; ni++) bq[ni] = *(const bf16x8*)&Bs[(ni * 16 + fr) * 32 + fk];
#pragma unroll
    for (int mi = 0; mi < 2; mi++)
#pragma unroll
      for (int ni = 0; ni < 8; ni++)
        acc[mi][ni] = __builtin_amdgcn_mfma_f32_16x16x32_bf16(af[mi], bq[ni], acc[mi][ni], 0, 0, 0);
  }

  // epilogue: bias, rope, write q_bf[((b*1024+s)... -> [bh][s][d]]
  float qv[2][8][4];
#pragma unroll
  for (int mi = 0; mi < 2; mi++)
#pragma unroll
    for (int ni = 0; ni < 8; ni++) {
      float bv = bias[h * 128 + ni * 16 + fr];
#pragma unroll
      for (int i = 0; i < 4; i++) qv[mi][ni][i] = acc[mi][ni][i] + bv;
    }
#pragma unroll
  for (int mi = 0; mi < 2; mi++)
#pragma unroll
    for (int i = 0; i < 4; i++) {
      int row = row0 + wr + mi * 16 + fg * 4 + i;     // b*1024 + s
      int s = row & 1023, bb = row >> 10;
      size_t obase = (((size_t)(bb * 16 + h)) * 1024 + s) * 128;
#pragma unroll
      for (int ni = 0; ni < 4; ni++) {
        int d = ni * 16 + fr;                          // 0..63
        float c  = cosb[s * 128 + d];
        float sn = sinb[s * 128 + d];                  // cos/sin[d+64] == [d]
        float lo = qv[mi][ni][i] * c - qv[mi][ni + 4][i] * sn;
        float hi = qv[mi][ni + 4][i] * c + qv[mi][ni][i] * sn;
        qout[obase + d]      = f2bf(lo);
        qout[obase + d + 64] = f2bf(hi);
      }
    }
}

// ---------------- Barrier-free per-wave flash attention (causal) ----------------
// 1024 waves (256 blocks x 4). Wave gw: bh = gw>>4, jp = gw&15; processes the
// q-tile pair {jp, 31-jp} (32 rows each) -> uniform 17 kv-tiles (BKV=64) per wave.
// K/V fragments read directly from L2 (kT[bh][s][d], vT[bh][d][s], bf16).
// P routed through wave-private padded LDS. No __syncthreads anywhere.
__global__ __launch_bounds__(256)
void attn_kernel(const u16* __restrict__ qbf, const u16* __restrict__ kTb,
                 const u16* __restrict__ vTb, u16* __restrict__ aout) {
  __shared__ __align__(16) u16 Pbuf[4][32 * 72];
  const int lane = threadIdx.x & 63, w = threadIdx.x >> 6;
  const int gw = blockIdx.x * 4 + w;
  const int bh = gw >> 4, jp = gw & 15;
  const int b = bh >> 4, h = bh & 15;
  const int fr = lane & 15, fg = lane >> 4;
  const float scale = 0.088388347648318447f;          // 1/sqrt(128)
  const u16* kbase = kTb + (size_t)bh * 131072;
  const u16* vbase = vTb + (size_t)bh * 131072;
  u16* Pw = Pbuf[w];

  for (int pass = 0; pass < 2; pass++) {
    const int j = pass ? 31 - jp : jp;
    const int q0 = j * 32;
    const int ntiles = (j >> 1) + 1;
    bf16x8 qf[2][4];
#pragma unroll
    for (int mi = 0; mi < 2; mi++)
#pragma unroll
      for (int kb = 0; kb < 4; kb++)
        qf[mi][kb] = *(const bf16x8*)&qbf[((size_t)bh * 1024 + q0 + mi * 16 + fr) * 128 + kb * 32 + fg * 8];
    f32x4 acc[2][8] = {};
    float m[2][4], l[2][4];
#pragma unroll
    for (int mi = 0; mi < 2; mi++)
#pragma unroll
      for (int i = 0; i < 4; i++) { m[mi][i] = -3e38f; l[mi][i] = 0.f; }

    for (int kt = 0; kt < ntiles; kt++) {
      // QK^T: S[q][kv], frags direct from L2
      f32x4 sa[2][4] = {};
#pragma unroll
      for (int kb = 0; kb < 4; kb++) {
        bf16x8 kf[4];
#pragma unroll
        for (int ni = 0; ni < 4; ni++)
          kf[ni] = *(const bf16x8*)&kbase[(size_t)(kt * 64 + ni * 16 + fr) * 128 + kb * 32 + fg * 8];
#pragma unroll
        for (int mi = 0; mi < 2; mi++)
#pragma unroll
          for (int ni = 0; ni < 4; ni++)
            sa[mi][ni] = __builtin_amdgcn_mfma_f32_16x16x32_bf16(qf[mi][kb], kf[ni], sa[mi][ni], 0, 0, 0);
      }
      // V fragment preload (latency hides under softmax)
      bf16x8 vf[8][2];
#pragma unroll
      for (int ni = 0; ni < 8; ni++)
#pragma unroll
        for (int k2 = 0; k2 < 2; k2++)
          vf[ni][k2] = *(const bf16x8*)&vbase[(size_t)(ni * 16 + fr) * 1024 + kt * 64 + k2 * 32 + fg * 8];

      // online softmax (rows = q0 + mi*16 + fg*4 + i; cols = kt*64 + ni*16 + fr)
#pragma unroll
      for (int mi = 0; mi < 2; mi++) {
        float tmax[4] = {-3e38f, -3e38f, -3e38f, -3e38f};
#pragma unroll
        for (int ni = 0; ni < 4; ni++) {
          int colg = kt * 64 + ni * 16 + fr;
#pragma unroll
          for (int i = 0; i < 4; i++) {
            int rowg = q0 + mi * 16 + fg * 4 + i;
            float s = sa[mi][ni][i] * scale;
            if (colg > rowg) s = -1e9f;
            sa[mi][ni][i] = s;
            tmax[i] = fmaxf(tmax[i], s);
          }
        }
#pragma unroll
        for (int msk = 1; msk < 16; msk <<= 1)
#pragma unroll
          for (int i = 0; i < 4; i++) tmax[i] = fmaxf(tmax[i], __shfl_xor(tmax[i], msk));
        float corr[4];
#pragma unroll
        for (int i = 0; i < 4; i++) {
          float mn = fmaxf(m[mi][i], tmax[i]);
          corr[i] = __expf(m[mi][i] - mn);
          m[mi][i] = mn;
        }
        float rs[4] = {0.f, 0.f, 0.f, 0.f};
#pragma unroll
        for (int ni = 0; ni < 4; ni++)
#pragma unroll
          for (int i = 0; i < 4; i++) {
            float p = __expf(sa[mi][ni][i] - m[mi][i]);
            sa[mi][ni][i] = p;
            rs[i] += p;
          }
#pragma unroll
        for (int msk = 1; msk < 16; msk <<= 1)
#pragma unroll
          for (int i = 0; i < 4; i++) rs[i] += __shfl_xor(rs[i], msk);
#pragma unroll
        for (int i = 0; i < 4; i++) l[mi][i] = l[mi][i] * corr[i] + rs[i];
#pragma unroll
        for (int ni = 0; ni < 8; ni++)
#pragma unroll
          for (int i = 0; i < 4; i++) acc[mi][ni][i] *= corr[i];
#pragma unroll
        for (int ni = 0; ni < 4; ni++)
#pragma unroll
          for (int i = 0; i < 4; i++)
            Pw[(mi * 16 + fg * 4 + i) * 72 + ni * 16 + fr] = f2bf(sa[mi][ni][i]);
      }
      // PV: O += P @ V (wave-private P, preloaded V frags)
#pragma unroll
      for (int k2 = 0; k2 < 2; k2++) {
        bf16x8 pf[2];
#pragma unroll
        for (int mi = 0; mi < 2; mi++)
          pf[mi] = *(const bf16x8*)&Pw[(mi * 16 + fr) * 72 + k2 * 32 + fg * 8];
#pragma unroll
        for (int ni = 0; ni < 8; ni++)
#pragma unroll
          for (int mi = 0; mi < 2; mi++)
            acc[mi][ni] = __builtin_amdgcn_mfma_f32_16x16x32_bf16(pf[mi], vf[ni][k2], acc[mi][ni], 0, 0, 0);
      }
    }
    // epilogue: attn_bf[((b*S+s)*NH+h)*HD + d]
#pragma unroll
    for (int mi = 0; mi < 2; mi++)
#pragma unroll
      for (int i = 0; i < 4; i++) {
        int s = q0 + mi * 16 + fg * 4 + i;
        float inv = 1.f / l[mi][i];
#pragma unroll
        for (int ni = 0; ni < 8; ni++)
          aout[(((size_t)b * 1024 + s) * 16 + h) * 128 + ni * 16 + fr] = f2bf(acc[mi][ni][i] * inv);
      }
  }
}

// ---------------- launcher ----------------
extern "C" void kernel_launch(void* const* d_in, const int* in_sizes, int n_in,
                              void* d_out, int out_size, void* d_ws, size_t ws_size,
                              hipStream_t stream) {
  const float* hs  = (const float*)d_in[0];
  const float* key = (const float*)d_in[1];
  const float* val = (const float*)d_in[2];
  // d_in[3]: attention_mask — causal, reproduced analytically
  const float* rc  = (const float*)d_in[4];
  const float* rs  = (const float*)d_in[5];
  const float* wq  = (const float*)d_in[6];
  const float* bq  = (const float*)d_in[7];
  const float* wo  = (const float*)d_in[8];
  const float* bo  = (const float*)d_in[9];
  float* out = (float*)d_out;

  char* ws = (char*)d_ws;
  u16* hs_bf = (u16*)(ws);                   // 16 MB ; reused as attn_bf
  u16* wq_bf = (u16*)(ws + 16777216);        //  8 MB
  u16* wo_bf = (u16*)(ws + 25165824);        //  8 MB
  u16* q_bf  = (u16*)(ws + 33554432);        // 16 MB
  u16* kT    = (u16*)(ws + 50331648);        // 16 MB  [bh][s][d]
  u16* vT    = (u16*)(ws + 67108864);        // 16 MB  [bh][d][s]   (total 80 MB)
  u16* attn_bf = hs_bf;                      // hs_bf dead after gemm_rope

  cvt_kernel<<<8192, 256, 0, stream>>>(hs, hs_bf, 8388608 / 4);
  cvt_kernel<<<4096, 256, 0, stream>>>(wq, wq_bf, 4194304 / 4);
  cvt_kernel<<<4096, 256, 0, stream>>>(wo, wo_bf, 4194304 / 4);

  transpose_cvt<<<dim3(64, 128), 256, 0, stream>>>(key, kT, 128, 1024);   // -> kT[bh][s][d]
  transpose_cvt<<<dim3(64, 128), 256, 0, stream>>>(val, vT, 1024, 128);   // -> vT[bh][d][s]

  gemm_rope<<<dim3(32, 16), 256, 0, stream>>>(hs_bf, wq_bf, bq, rc, rs, q_bf);
  attn_kernel<<<256, 256, 0, stream>>>(q_bf, kT, vT, attn_bf);
  gemm_bt<false><<<dim3(32, 16), 256, 0, stream>>>(attn_bf, wo_bf, bo, out, 4096, 2048, 2048);
}

// Round 4
// 183.824 us; speedup vs baseline: 1.1890x; 1.1890x over previous
//
#include <hip/hip_runtime.h>
#include <cstdint>

// CrossLayerAttention on MI355X (gfx950).  B=4 S=1024 H=2048 NH=16 HD=128.
// R4: double-buffered LDS-staged flash attention (gld16 + XOR-swizzle per
//     rule #21, 8 waves, balanced causal pairs, XCD-grouped grid).
//     GEMMs unchanged from R3 (m97 structure, RoPE fused in Q-proj epilogue).

typedef unsigned short u16;
typedef __bf16 bf16x8 __attribute__((ext_vector_type(8)));
typedef float  f32x4  __attribute__((ext_vector_type(4)));

__device__ __forceinline__ u16 f2bf(float f) {
  uint32_t u = __builtin_bit_cast(uint32_t, f);
  u += 0x7fffu + ((u >> 16) & 1u);   // RNE; inputs finite
  return (u16)(u >> 16);
}
__device__ __forceinline__ float bf2f(u16 h) {
  uint32_t u = ((uint32_t)h) << 16;
  return __builtin_bit_cast(float, u);
}
__device__ __forceinline__ void gld16(const void* g, void* l) {
  __builtin_amdgcn_global_load_lds(
      (const __attribute__((address_space(1))) void*)g,
      (__attribute__((address_space(3))) void*)l, 16, 0, 0);
}

// ---------------- fp32 -> bf16 convert ----------------
__global__ __launch_bounds__(256) void cvt_kernel(const float* __restrict__ in,
                                                  u16* __restrict__ out, int n4) {
  int i = blockIdx.x * 256 + threadIdx.x;
  if (i < n4) {
    float4 v = ((const float4*)in)[i];
    ushort4 o;
    o.x = f2bf(v.x); o.y = f2bf(v.y); o.z = f2bf(v.z); o.w = f2bf(v.w);
    ((ushort4*)out)[i] = o;
  }
}

// ---------------- per-bh transpose + cvt: out[c][r] = bf16(in[r][c]) ----------------
__global__ __launch_bounds__(256) void transpose_cvt(const float* __restrict__ in,
                                                     u16* __restrict__ out, int R, int C) {
  __shared__ float tile[32][33];
  const int bh = blockIdx.x;
  const int nct = C >> 5;
  const int rt = blockIdx.y / nct, ct = blockIdx.y % nct;
  const float* src = in + (size_t)bh * R * C;
  u16* dst = out + (size_t)bh * R * C;
  const int r = threadIdx.x >> 3, c4 = (threadIdx.x & 7) * 4;
  float4 v = *(const float4*)(src + (size_t)(rt * 32 + r) * C + ct * 32 + c4);
  tile[r][c4 + 0] = v.x; tile[r][c4 + 1] = v.y;
  tile[r][c4 + 2] = v.z; tile[r][c4 + 3] = v.w;
  __syncthreads();
  ushort4 o;
  o.x = f2bf(tile[c4 + 0][r]); o.y = f2bf(tile[c4 + 1][r]);
  o.z = f2bf(tile[c4 + 2][r]); o.w = f2bf(tile[c4 + 3][r]);
  *(ushort4*)(dst + (size_t)(ct * 32 + r) * R + rt * 32 + c4) = o;
}

// ---------------- GEMM (out-proj): C[M,N] = A[M,K] @ B[N,K]^T + bias ----------------
template<bool OUT_BF16>
__global__ __launch_bounds__(256, 2)
void gemm_bt(const u16* __restrict__ A, const u16* __restrict__ Bm,
             const float* __restrict__ bias, void* __restrict__ Cout,
             int M, int N, int K) {
  __shared__ __align__(16) u16 As[128 * 32];
  __shared__ __align__(16) u16 Bs[128 * 32];
  const int t = threadIdx.x, lane = t & 63, w = t >> 6;
  const int row0 = blockIdx.x * 128, col0 = blockIdx.y * 128;
  const int wr = (w >> 1) * 64, wc = (w & 1) * 64;
  const int fr = lane & 15, fg = lane >> 4, fk = fg * 8;
  const int srow = w * 32 + (lane >> 2), scol = (lane & 3) * 8;
  const u16* gA0 = A  + (size_t)(row0 + srow) * K + scol;
  const u16* gB0 = Bm + (size_t)(col0 + srow) * K + scol;
  u16* lA0 = As + (w * 32) * 32;
  u16* lA1 = As + (w * 32 + 16) * 32;
  u16* lB0 = Bs + (w * 32) * 32;
  u16* lB1 = Bs + (w * 32 + 16) * 32;
  f32x4 acc[4][4] = {};

  for (int k0 = 0; k0 < K; k0 += 32) {
    __syncthreads();
    gld16(gA0 + k0, lA0);
    gld16(gA0 + k0 + (size_t)16 * K, lA1);
    gld16(gB0 + k0, lB0);
    gld16(gB0 + k0 + (size_t)16 * K, lB1);
    __syncthreads();
    bf16x8 af[4], bq[4];
#pragma unroll
    for (int i = 0; i < 4; i++) af[i] = *(const bf16x8*)&As[(wr + i * 16 + fr) * 32 + fk];
#pragma unroll
    for (int i = 0; i < 4; i++) bq[i] = *(const bf16x8*)&Bs[(wc + i * 16 + fr) * 32 + fk];
#pragma unroll
    for (int mi = 0; mi < 4; mi++)
#pragma unroll
      for (int ni = 0; ni < 4; ni++)
        acc[mi][ni] = __builtin_amdgcn_mfma_f32_16x16x32_bf16(af[mi], bq[ni], acc[mi][ni], 0, 0, 0);
  }

#pragma unroll
  for (int mi = 0; mi < 4; mi++)
#pragma unroll
    for (int ni = 0; ni < 4; ni++) {
      int col = col0 + wc + ni * 16 + fr;
      float bv = bias[col];
#pragma unroll
      for (int i = 0; i < 4; i++) {
        int row = row0 + wr + mi * 16 + fg * 4 + i;
        float v = acc[mi][ni][i] + bv;
        if constexpr (OUT_BF16) ((u16*)Cout)[(size_t)row * N + col] = f2bf(v);
        else                    ((float*)Cout)[(size_t)row * N + col] = v;
      }
    }
}

// ---------------- Q-proj GEMM with fused RoPE epilogue ----------------
__global__ __launch_bounds__(256, 2)
void gemm_rope(const u16* __restrict__ A, const u16* __restrict__ Bm,
               const float* __restrict__ bias, const float* __restrict__ cosb,
               const float* __restrict__ sinb, u16* __restrict__ qout) {
  __shared__ __align__(16) u16 As[128 * 32];
  __shared__ __align__(16) u16 Bs[128 * 32];
  const int K = 2048;
  const int t = threadIdx.x, lane = t & 63, w = t >> 6;
  const int row0 = blockIdx.x * 128, h = blockIdx.y;
  const int wr = w * 32;
  const int fr = lane & 15, fg = lane >> 4, fk = fg * 8;
  const int srow = w * 32 + (lane >> 2), scol = (lane & 3) * 8;
  const u16* gA0 = A  + (size_t)(row0 + srow) * K + scol;
  const u16* gB0 = Bm + (size_t)(h * 128 + srow) * K + scol;
  u16* lA0 = As + (w * 32) * 32;
  u16* lA1 = As + (w * 32 + 16) * 32;
  u16* lB0 = Bs + (w * 32) * 32;
  u16* lB1 = Bs + (w * 32 + 16) * 32;
  f32x4 acc[2][8] = {};

  for (int k0 = 0; k0 < K; k0 += 32) {
    __syncthreads();
    gld16(gA0 + k0, lA0);
    gld16(gA0 + k0 + (size_t)16 * K, lA1);
    gld16(gB0 + k0, lB0);
    gld16(gB0 + k0 + (size_t)16 * K, lB1);
    __syncthreads();
    bf16x8 af[2], bq[8];
#pragma unroll
    for (int mi = 0; mi < 2; mi++) af[mi] = *(const bf16x8*)&As[(wr + mi * 16 + fr) * 32 + fk];
#pragma unroll
    for (int ni = 0; ni < 8; ni++) bq[ni] = *(const bf16x8*)&Bs[(ni * 16 + fr) * 32 + fk];
#pragma unroll
    for (int mi = 0; mi < 2; mi++)
#pragma unroll
      for (int ni = 0; ni < 8; ni++)
        acc[mi][ni] = __builtin_amdgcn_mfma_f32_16x16x32_bf16(af[mi], bq[ni], acc[mi][ni], 0, 0, 0);
  }

  float qv[2][8][4];
#pragma unroll
  for (int mi = 0; mi < 2; mi++)
#pragma unroll
    for (int ni = 0; ni < 8; ni++) {
      float bv = bias[h * 128 + ni * 16 + fr];
#pragma unroll
      for (int i = 0; i < 4; i++) qv[mi][ni][i] = acc[mi][ni][i] + bv;
    }
#pragma unroll
  for (int mi = 0; mi < 2; mi++)
#pragma unroll
    for (int i = 0; i < 4; i++) {
      int row = row0 + wr + mi * 16 + fg * 4 + i;     // b*1024 + s
      int s = row & 1023, bb = row >> 10;
      size_t obase = (((size_t)(bb * 16 + h)) * 1024 + s) * 128;
#pragma unroll
      for (int ni = 0; ni < 4; ni++) {
        int d = ni * 16 + fr;                          // 0..63
        float c  = cosb[s * 128 + d];
        float sn = sinb[s * 128 + d];
        float lo = qv[mi][ni][i] * c - qv[mi][ni + 4][i] * sn;
        float hi = qv[mi][ni + 4][i] * c + qv[mi][ni][i] * sn;
        qout[obase + d]      = f2bf(lo);
        qout[obase + d + 64] = f2bf(hi);
      }
    }
}

// ---------------- Flash attention: 2-phase dbuf, swizzled LDS ----------------
// 256 blocks x 512 thr (8 waves). Block x: bh=(x&7)+8*(x>>5) (XCD-grouped),
// jp=(x>>3)&3; q-tile pair {jp, 7-jp} of BQ=128 -> uniform 18 kv-tiles (BKV=64).
// K tile [64][128], V^T tile [128][64] staged via gld16 with inverse-swizzled
// global source; ds_read applies XOR swizzle (rule #21). P wave-private LDS.
__global__ __launch_bounds__(512)
void attn_kernel(const u16* __restrict__ qbf, const u16* __restrict__ kTb,
                 const u16* __restrict__ vTb, u16* __restrict__ aout) {
  __shared__ __align__(16) u16 Kb[2][64 * 128];   // 2 x 16 KB
  __shared__ __align__(16) u16 Vb[2][128 * 64];   // 2 x 16 KB
  __shared__ __align__(16) u16 Pb[8][16 * 72];    // 18 KB
  const int t = threadIdx.x, lane = t & 63, w = t >> 6;
  const int x = blockIdx.x;
  const int bh = (x & 7) + 8 * (x >> 5);
  const int jp = (x >> 3) & 3;
  const int b = bh >> 4, h = bh & 15;
  const int fr = lane & 15, fg = lane >> 4;
  const float scale = 0.088388347648318447f;      // 1/sqrt(128)
  const u16* kbase = kTb + (size_t)bh * 131072;   // [s][d]
  const u16* vbase = vTb + (size_t)bh * 131072;   // [d][s]
  u16* Pw = Pb[w];

  // Staging geometry (lane-constant). K inst p covers tile rows w*8+p*4+fg,
  // source col pre-swizzled so linear LDS + swizzled read line up (rule #21).
  const int rK0 = w * 8 + fg,     cK0 = (fr ^ fg) * 8;
  const int rK1 = w * 8 + 4 + fg, cK1 = (fr ^ (4 + fg)) * 8;
  const int rV0 = w * 16 + (lane >> 3), rV1 = rV0 + 8;
  const int cV  = ((lane & 7) ^ ((lane >> 3) & 7)) * 8;
  const int frs = fr & 7;                          // read-side swizzle key

  for (int pass = 0; pass < 2; pass++) {
    const int j = pass ? 7 - jp : jp;
    const int q0 = j * 128;
    const int ntiles = 2 * j + 2;
    bf16x8 qf[4];
#pragma unroll
    for (int kb = 0; kb < 4; kb++)
      qf[kb] = *(const bf16x8*)&qbf[((size_t)bh * 1024 + q0 + w * 16 + fr) * 128 + kb * 32 + fg * 8];
    f32x4 acc[8] = {};
    float m[4], l[4];
#pragma unroll
    for (int i = 0; i < 4; i++) { m[i] = -3e38f; l[i] = 0.f; }

    auto STAGE = [&](int kt, int buf) {
      const u16* ks = kbase + (size_t)(kt * 64) * 128;
      const u16* vs = vbase + kt * 64;
      u16* kl = &Kb[buf][w * 1024];
      u16* vl = &Vb[buf][w * 1024];
      gld16(ks + rK0 * 128 + cK0, kl);
      gld16(ks + rK1 * 128 + cK1, kl + 512);
      gld16(vs + (size_t)rV0 * 1024 + cV, vl);
      gld16(vs + (size_t)rV1 * 1024 + cV, vl + 512);
    };

    STAGE(0, 0);
    __syncthreads();
    int cur = 0;
    for (int kt = 0; kt < ntiles; kt++) {
      if (kt + 1 < ntiles) STAGE(kt + 1, cur ^ 1);
      // QK^T: 16 q-rows x 64 kv-cols, swizzled K reads
      f32x4 sa[4] = {};
#pragma unroll
      for (int kb = 0; kb < 4; kb++) {
        bf16x8 kf[4];
#pragma unroll
        for (int ni = 0; ni < 4; ni++)
          kf[ni] = *(const bf16x8*)&Kb[cur][(ni * 16 + fr) * 128 + (((kb * 4 + fg) ^ frs) * 8)];
#pragma unroll
        for (int ni = 0; ni < 4; ni++)
          sa[ni] = __builtin_amdgcn_mfma_f32_16x16x32_bf16(qf[kb], kf[ni], sa[ni], 0, 0, 0);
      }
      // online softmax; rows = q0 + w*16 + fg*4 + i, cols = kt*64 + ni*16 + fr
      const bool diag = (kt >= 2 * j);
      float tmax[4] = {-3e38f, -3e38f, -3e38f, -3e38f};
      if (diag) {
#pragma unroll
        for (int ni = 0; ni < 4; ni++) {
          int colg = kt * 64 + ni * 16 + fr;
#pragma unroll
          for (int i = 0; i < 4; i++) {
            int rowg = q0 + w * 16 + fg * 4 + i;
            float s = sa[ni][i] * scale;
            if (colg > rowg) s = -1e9f;
            sa[ni][i] = s;
            tmax[i] = fmaxf(tmax[i], s);
          }
        }
      } else {
#pragma unroll
        for (int ni = 0; ni < 4; ni++)
#pragma unroll
          for (int i = 0; i < 4; i++) {
            float s = sa[ni][i] * scale;
            sa[ni][i] = s;
            tmax[i] = fmaxf(tmax[i], s);
          }
      }
#pragma unroll
      for (int msk = 1; msk < 16; msk <<= 1)
#pragma unroll
        for (int i = 0; i < 4; i++) tmax[i] = fmaxf(tmax[i], __shfl_xor(tmax[i], msk));
      float corr[4];
#pragma unroll
      for (int i = 0; i < 4; i++) {
        float mn = fmaxf(m[i], tmax[i]);
        corr[i] = __expf(m[i] - mn);
        m[i] = mn;
      }
      float rs[4] = {0.f, 0.f, 0.f, 0.f};
#pragma unroll
      for (int ni = 0; ni < 4; ni++)
#pragma unroll
        for (int i = 0; i < 4; i++) {
          float p = __expf(sa[ni][i] - m[i]);
          sa[ni][i] = p;
          rs[i] += p;
        }
#pragma unroll
      for (int msk = 1; msk < 16; msk <<= 1)
#pragma unroll
        for (int i = 0; i < 4; i++) rs[i] += __shfl_xor(rs[i], msk);
#pragma unroll
      for (int i = 0; i < 4; i++) l[i] = l[i] * corr[i] + rs[i];
#pragma unroll
      for (int ni = 0; ni < 8; ni++)
#pragma unroll
        for (int i = 0; i < 4; i++) acc[ni][i] *= corr[i];
#pragma unroll
      for (int ni = 0; ni < 4; ni++)
#pragma unroll
        for (int i = 0; i < 4; i++)
          Pw[(fg * 4 + i) * 72 + ni * 16 + fr] = f2bf(sa[ni][i]);
      // PV: O += P @ V (wave-private P, swizzled V reads)
#pragma unroll
      for (int k2 = 0; k2 < 2; k2++) {
        bf16x8 pf = *(const bf16x8*)&Pw[fr * 72 + k2 * 32 + fg * 8];
#pragma unroll
        for (int ni = 0; ni < 8; ni++) {
          bf16x8 vf = *(const bf16x8*)&Vb[cur][(ni * 16 + fr) * 64 + (((k2 * 4 + fg) ^ frs) * 8)];
          acc[ni] = __builtin_amdgcn_mfma_f32_16x16x32_bf16(pf, vf, acc[ni], 0, 0, 0);
        }
      }
      __syncthreads();                             // drains vmcnt: t+1 staged
      cur ^= 1;
    }
    // epilogue: attn_bf[((b*S+s)*NH+h)*HD + d]
#pragma unroll
    for (int i = 0; i < 4; i++) {
      int s = q0 + w * 16 + fg * 4 + i;
      float inv = 1.f / l[i];
#pragma unroll
      for (int ni = 0; ni < 8; ni++)
        aout[(((size_t)b * 1024 + s) * 16 + h) * 128 + ni * 16 + fr] = f2bf(acc[ni][i] * inv);
    }
  }
}

// ---------------- launcher ----------------
extern "C" void kernel_launch(void* const* d_in, const int* in_sizes, int n_in,
                              void* d_out, int out_size, void* d_ws, size_t ws_size,
                              hipStream_t stream) {
  const float* hs  = (const float*)d_in[0];
  const float* key = (const float*)d_in[1];
  const float* val = (const float*)d_in[2];
  // d_in[3]: attention_mask — causal, reproduced analytically
  const float* rc  = (const float*)d_in[4];
  const float* rs  = (const float*)d_in[5];
  const float* wq  = (const float*)d_in[6];
  const float* bq  = (const float*)d_in[7];
  const float* wo  = (const float*)d_in[8];
  const float* bo  = (const float*)d_in[9];
  float* out = (float*)d_out;

  char* ws = (char*)d_ws;
  u16* hs_bf = (u16*)(ws);                   // 16 MB ; reused as attn_bf
  u16* wq_bf = (u16*)(ws + 16777216);        //  8 MB
  u16* wo_bf = (u16*)(ws + 25165824);        //  8 MB
  u16* q_bf  = (u16*)(ws + 33554432);        // 16 MB
  u16* kT    = (u16*)(ws + 50331648);        // 16 MB  [bh][s][d]
  u16* vT    = (u16*)(ws + 67108864);        // 16 MB  [bh][d][s]
  u16* attn_bf = hs_bf;                      // hs_bf dead after gemm_rope

  cvt_kernel<<<8192, 256, 0, stream>>>(hs, hs_bf, 8388608 / 4);
  cvt_kernel<<<4096, 256, 0, stream>>>(wq, wq_bf, 4194304 / 4);
  cvt_kernel<<<4096, 256, 0, stream>>>(wo, wo_bf, 4194304 / 4);

  transpose_cvt<<<dim3(64, 128), 256, 0, stream>>>(key, kT, 128, 1024);   // -> kT[bh][s][d]
  transpose_cvt<<<dim3(64, 128), 256, 0, stream>>>(val, vT, 1024, 128);   // -> vT[bh][d][s]

  gemm_rope<<<dim3(32, 16), 256, 0, stream>>>(hs_bf, wq_bf, bq, rc, rs, q_bf);
  attn_kernel<<<256, 512, 0, stream>>>(q_bf, kT, vT, attn_bf);
  gemm_bt<false><<<dim3(32, 16), 256, 0, stream>>>(attn_bf, wo_bf, bo, out, 4096, 2048, 2048);
}

// Round 5
// 179.998 us; speedup vs baseline: 1.2142x; 1.0213x over previous
//
#include <hip/hip_runtime.h>
#include <cstdint>

// CrossLayerAttention on MI355X (gfx950).  B=4 S=1024 H=2048 NH=16 HD=128.
// R5: attn -> 4-wave blocks, BQ=64, 2 blocks/CU (two barrier domains/CU),
//     defer-max (T13) + setprio (T5); gemm_rope -> 2x2 wave tiling with
//     interleaved col map so rope pairs stay in-wave.

typedef unsigned short u16;
typedef __bf16 bf16x8 __attribute__((ext_vector_type(8)));
typedef float  f32x4  __attribute__((ext_vector_type(4)));

__device__ __forceinline__ u16 f2bf(float f) {
  uint32_t u = __builtin_bit_cast(uint32_t, f);
  u += 0x7fffu + ((u >> 16) & 1u);   // RNE; inputs finite
  return (u16)(u >> 16);
}
__device__ __forceinline__ float bf2f(u16 h) {
  uint32_t u = ((uint32_t)h) << 16;
  return __builtin_bit_cast(float, u);
}
__device__ __forceinline__ void gld16(const void* g, void* l) {
  __builtin_amdgcn_global_load_lds(
      (const __attribute__((address_space(1))) void*)g,
      (__attribute__((address_space(3))) void*)l, 16, 0, 0);
}

// ---------------- fp32 -> bf16 convert ----------------
__global__ __launch_bounds__(256) void cvt_kernel(const float* __restrict__ in,
                                                  u16* __restrict__ out, int n4) {
  int i = blockIdx.x * 256 + threadIdx.x;
  if (i < n4) {
    float4 v = ((const float4*)in)[i];
    ushort4 o;
    o.x = f2bf(v.x); o.y = f2bf(v.y); o.z = f2bf(v.z); o.w = f2bf(v.w);
    ((ushort4*)out)[i] = o;
  }
}

// ---------------- per-bh transpose + cvt: out[c][r] = bf16(in[r][c]) ----------------
__global__ __launch_bounds__(256) void transpose_cvt(const float* __restrict__ in,
                                                     u16* __restrict__ out, int R, int C) {
  __shared__ float tile[32][33];
  const int bh = blockIdx.x;
  const int nct = C >> 5;
  const int rt = blockIdx.y / nct, ct = blockIdx.y % nct;
  const float* src = in + (size_t)bh * R * C;
  u16* dst = out + (size_t)bh * R * C;
  const int r = threadIdx.x >> 3, c4 = (threadIdx.x & 7) * 4;
  float4 v = *(const float4*)(src + (size_t)(rt * 32 + r) * C + ct * 32 + c4);
  tile[r][c4 + 0] = v.x; tile[r][c4 + 1] = v.y;
  tile[r][c4 + 2] = v.z; tile[r][c4 + 3] = v.w;
  __syncthreads();
  ushort4 o;
  o.x = f2bf(tile[c4 + 0][r]); o.y = f2bf(tile[c4 + 1][r]);
  o.z = f2bf(tile[c4 + 2][r]); o.w = f2bf(tile[c4 + 3][r]);
  *(ushort4*)(dst + (size_t)(ct * 32 + r) * R + rt * 32 + c4) = o;
}

// ---------------- GEMM (out-proj): C[M,N] = A[M,K] @ B[N,K]^T + bias ----------------
template<bool OUT_BF16>
__global__ __launch_bounds__(256, 2)
void gemm_bt(const u16* __restrict__ A, const u16* __restrict__ Bm,
             const float* __restrict__ bias, void* __restrict__ Cout,
             int M, int N, int K) {
  __shared__ __align__(16) u16 As[128 * 32];
  __shared__ __align__(16) u16 Bs[128 * 32];
  const int t = threadIdx.x, lane = t & 63, w = t >> 6;
  const int row0 = blockIdx.x * 128, col0 = blockIdx.y * 128;
  const int wr = (w >> 1) * 64, wc = (w & 1) * 64;
  const int fr = lane & 15, fg = lane >> 4, fk = fg * 8;
  const int srow = w * 32 + (lane >> 2), scol = (lane & 3) * 8;
  const u16* gA0 = A  + (size_t)(row0 + srow) * K + scol;
  const u16* gB0 = Bm + (size_t)(col0 + srow) * K + scol;
  u16* lA0 = As + (w * 32) * 32;
  u16* lA1 = As + (w * 32 + 16) * 32;
  u16* lB0 = Bs + (w * 32) * 32;
  u16* lB1 = Bs + (w * 32 + 16) * 32;
  f32x4 acc[4][4] = {};

  for (int k0 = 0; k0 < K; k0 += 32) {
    __syncthreads();
    gld16(gA0 + k0, lA0);
    gld16(gA0 + k0 + (size_t)16 * K, lA1);
    gld16(gB0 + k0, lB0);
    gld16(gB0 + k0 + (size_t)16 * K, lB1);
    __syncthreads();
    bf16x8 af[4], bq[4];
#pragma unroll
    for (int i = 0; i < 4; i++) af[i] = *(const bf16x8*)&As[(wr + i * 16 + fr) * 32 + fk];
#pragma unroll
    for (int i = 0; i < 4; i++) bq[i] = *(const bf16x8*)&Bs[(wc + i * 16 + fr) * 32 + fk];
#pragma unroll
    for (int mi = 0; mi < 4; mi++)
#pragma unroll
      for (int ni = 0; ni < 4; ni++)
        acc[mi][ni] = __builtin_amdgcn_mfma_f32_16x16x32_bf16(af[mi], bq[ni], acc[mi][ni], 0, 0, 0);
  }

#pragma unroll
  for (int mi = 0; mi < 4; mi++)
#pragma unroll
    for (int ni = 0; ni < 4; ni++) {
      int col = col0 + wc + ni * 16 + fr;
      float bv = bias[col];
#pragma unroll
      for (int i = 0; i < 4; i++) {
        int row = row0 + wr + mi * 16 + fg * 4 + i;
        float v = acc[mi][ni][i] + bv;
        if constexpr (OUT_BF16) ((u16*)Cout)[(size_t)row * N + col] = f2bf(v);
        else                    ((float*)Cout)[(size_t)row * N + col] = v;
      }
    }
}

// ---------------- Q-proj GEMM + fused RoPE, 2x2 wave tiling ----------------
// Block 128 rows x 128 cols (one head). Wave w: rows wr..wr+63, col group
// g=w&1; fragment ni -> col g*32 + (ni&1)*16 + (ni>>1)*64 + fr, so the rope
// pair (d, d+64) is (ni, ni+2) within the same wave.
__global__ __launch_bounds__(256, 2)
void gemm_rope(const u16* __restrict__ A, const u16* __restrict__ Bm,
               const float* __restrict__ bias, const float* __restrict__ cosb,
               const float* __restrict__ sinb, u16* __restrict__ qout) {
  __shared__ __align__(16) u16 As[128 * 32];
  __shared__ __align__(16) u16 Bs[128 * 32];
  const int K = 2048;
  const int t = threadIdx.x, lane = t & 63, w = t >> 6;
  const int row0 = blockIdx.x * 128, h = blockIdx.y;
  const int wr = (w >> 1) * 64, g = w & 1;
  const int fr = lane & 15, fg = lane >> 4, fk = fg * 8;
  const int srow = w * 32 + (lane >> 2), scol = (lane & 3) * 8;
  const u16* gA0 = A  + (size_t)(row0 + srow) * K + scol;
  const u16* gB0 = Bm + (size_t)(h * 128 + srow) * K + scol;
  u16* lA0 = As + (w * 32) * 32;
  u16* lA1 = As + (w * 32 + 16) * 32;
  u16* lB0 = Bs + (w * 32) * 32;
  u16* lB1 = Bs + (w * 32 + 16) * 32;
  f32x4 acc[4][4] = {};
  const int colr[4] = {g * 32 + fr, g * 32 + 16 + fr,
                       g * 32 + 64 + fr, g * 32 + 80 + fr};

  for (int k0 = 0; k0 < K; k0 += 32) {
    __syncthreads();
    gld16(gA0 + k0, lA0);
    gld16(gA0 + k0 + (size_t)16 * K, lA1);
    gld16(gB0 + k0, lB0);
    gld16(gB0 + k0 + (size_t)16 * K, lB1);
    __syncthreads();
    bf16x8 af[4], bq[4];
#pragma unroll
    for (int i = 0; i < 4; i++) af[i] = *(const bf16x8*)&As[(wr + i * 16 + fr) * 32 + fk];
#pragma unroll
    for (int ni = 0; ni < 4; ni++) bq[ni] = *(const bf16x8*)&Bs[colr[ni] * 32 + fk];
#pragma unroll
    for (int mi = 0; mi < 4; mi++)
#pragma unroll
      for (int ni = 0; ni < 4; ni++)
        acc[mi][ni] = __builtin_amdgcn_mfma_f32_16x16x32_bf16(af[mi], bq[ni], acc[mi][ni], 0, 0, 0);
  }

  // epilogue: bias + rope pairing (ni, ni+2) -> (d, d+64), d = g*32+dp*16+fr
  float bv[4];
#pragma unroll
  for (int ni = 0; ni < 4; ni++) bv[ni] = bias[h * 128 + colr[ni]];
#pragma unroll
  for (int mi = 0; mi < 4; mi++)
#pragma unroll
    for (int i = 0; i < 4; i++) {
      int row = row0 + wr + mi * 16 + fg * 4 + i;     // b*1024 + s
      int s = row & 1023, bb = row >> 10;
      size_t obase = (((size_t)(bb * 16 + h)) * 1024 + s) * 128;
#pragma unroll
      for (int dp = 0; dp < 2; dp++) {
        int d = g * 32 + dp * 16 + fr;                 // 0..63
        float c  = cosb[s * 128 + d];
        float sn = sinb[s * 128 + d];
        float qlo = acc[mi][dp][i] + bv[dp];
        float qhi = acc[mi][dp + 2][i] + bv[dp + 2];
        qout[obase + d]      = f2bf(qlo * c - qhi * sn);
        qout[obase + d + 64] = f2bf(qhi * c + qlo * sn);
      }
    }
}

// ---------------- Flash attention: 4 waves, BQ=64, 2 blocks/CU ----------------
// 512 blocks x 256 thr. Block x: xcd=x&7, i=x>>3; bh=(x&7)*8+(i&7) (8 blocks
// per bh co-located on one XCD -> 4MB K/V set = L2); jp=i>>3; q-tile pair
// {jp, 15-jp} of BQ=64 -> uniform 17 kv-tiles (BKV=64). Double-buffered
// swizzled K[64][128] / V^T[128][64] via gld16 (rule #21). Wave-private P.
__global__ __launch_bounds__(256, 2)
void attn_kernel(const u16* __restrict__ qbf, const u16* __restrict__ kTb,
                 const u16* __restrict__ vTb, u16* __restrict__ aout) {
  __shared__ __align__(16) u16 Kb[2][64 * 128];   // 2 x 16 KB
  __shared__ __align__(16) u16 Vb[2][128 * 64];   // 2 x 16 KB
  __shared__ __align__(16) u16 Pb[4][16 * 72];    // 9 KB
  const int t = threadIdx.x, lane = t & 63, w = t >> 6;
  const int x = blockIdx.x;
  const int xi = x >> 3;
  const int bh = (x & 7) * 8 + (xi & 7);
  const int jp = xi >> 3;
  const int b = bh >> 4, h = bh & 15;
  const int fr = lane & 15, fg = lane >> 4, frs = fr & 7;
  const float scale = 0.088388347648318447f;      // 1/sqrt(128)
  const u16* kbase = kTb + (size_t)bh * 131072;   // [s][d]
  const u16* vbase = vTb + (size_t)bh * 131072;   // [d][s]
  u16* Pw = Pb[w];

  // staging geometry: K slot = p*256+t (16B), row p*16+(t>>4), col (t&15)^key
  const int kr  = t >> 4;                          // key = kr&7 (const over p)
  const int kcs = ((t & 15) ^ (kr & 7)) * 8;
  const int vr  = t >> 3;                          // V: row p*32+vr
  const int vcs = ((t & 7) ^ (vr & 7)) * 8;

  for (int pass = 0; pass < 2; pass++) {
    const int j = pass ? 15 - jp : jp;
    const int q0 = j * 64;
    const int ntiles = j + 1;
    bf16x8 qf[4];
#pragma unroll
    for (int kb = 0; kb < 4; kb++)
      qf[kb] = *(const bf16x8*)&qbf[((size_t)bh * 1024 + q0 + w * 16 + fr) * 128 + kb * 32 + fg * 8];
    f32x4 acc[8] = {};
    float m[4], l[4];
#pragma unroll
    for (int i = 0; i < 4; i++) { m[i] = -3e38f; l[i] = 0.f; }

    auto STAGE = [&](int kt, int buf) {
      const u16* ks = kbase + (size_t)(kt * 64) * 128;
      const u16* vs = vbase + kt * 64;
#pragma unroll
      for (int p = 0; p < 4; p++)
        gld16(ks + (size_t)(p * 16 + kr) * 128 + kcs, &Kb[buf][(p * 256 + t) * 8]);
#pragma unroll
      for (int p = 0; p < 4; p++)
        gld16(vs + (size_t)(p * 32 + vr) * 1024 + vcs, &Vb[buf][(p * 256 + t) * 8]);
    };

    STAGE(0, 0);
    __syncthreads();
    int cur = 0;
    for (int kt = 0; kt < ntiles; kt++) {
      if (kt + 1 < ntiles) STAGE(kt + 1, cur ^ 1);
      // QK^T: 16 q-rows x 64 kv-cols, swizzled K reads
      f32x4 sa[4] = {};
      __builtin_amdgcn_s_setprio(1);
#pragma unroll
      for (int kb = 0; kb < 4; kb++) {
        bf16x8 kf[4];
#pragma unroll
        for (int ni = 0; ni < 4; ni++)
          kf[ni] = *(const bf16x8*)&Kb[cur][(ni * 16 + fr) * 128 + (((kb * 4 + fg) ^ frs) * 8)];
#pragma unroll
        for (int ni = 0; ni < 4; ni++)
          sa[ni] = __builtin_amdgcn_mfma_f32_16x16x32_bf16(qf[kb], kf[ni], sa[ni], 0, 0, 0);
      }
      __builtin_amdgcn_s_setprio(0);
      // online softmax; rows = w*16 + fg*4 + i (local), cols = ni*16 + fr
      const bool diag = (kt == j);
      float tmax[4] = {-3e38f, -3e38f, -3e38f, -3e38f};
      if (diag) {
        const int rloc = w * 16 + fg * 4;
#pragma unroll
        for (int ni = 0; ni < 4; ni++) {
          int cloc = ni * 16 + fr;
#pragma unroll
          for (int i = 0; i < 4; i++) {
            float s = sa[ni][i] * scale;
            if (cloc > rloc + i) s = -1e9f;
            sa[ni][i] = s;
            tmax[i] = fmaxf(tmax[i], s);
          }
        }
      } else {
#pragma unroll
        for (int ni = 0; ni < 4; ni++)
#pragma unroll
          for (int i = 0; i < 4; i++) {
            float s = sa[ni][i] * scale;
            sa[ni][i] = s;
            tmax[i] = fmaxf(tmax[i], s);
          }
      }
#pragma unroll
      for (int msk = 1; msk < 16; msk <<= 1)
#pragma unroll
        for (int i = 0; i < 4; i++) tmax[i] = fmaxf(tmax[i], __shfl_xor(tmax[i], msk));
      // defer-max (T13): skip rescale when max growth <= 8 (P <= e^8, bf16-safe)
      float need = fmaxf(fmaxf(tmax[0] - m[0], tmax[1] - m[1]),
                         fmaxf(tmax[2] - m[2], tmax[3] - m[3]));
      if (!__all(need <= 8.f)) {
#pragma unroll
        for (int i = 0; i < 4; i++) {
          float mn = fmaxf(m[i], tmax[i]);
          float corr = __expf(m[i] - mn);
          m[i] = mn;
          l[i] *= corr;
#pragma unroll
          for (int ni = 0; ni < 8; ni++) acc[ni][i] *= corr;
        }
      }
      float rs[4] = {0.f, 0.f, 0.f, 0.f};
#pragma unroll
      for (int ni = 0; ni < 4; ni++)
#pragma unroll
        for (int i = 0; i < 4; i++) {
          float p = __expf(sa[ni][i] - m[i]);
          sa[ni][i] = p;
          rs[i] += p;
        }
#pragma unroll
      for (int msk = 1; msk < 16; msk <<= 1)
#pragma unroll
        for (int i = 0; i < 4; i++) rs[i] += __shfl_xor(rs[i], msk);
#pragma unroll
      for (int i = 0; i < 4; i++) l[i] += rs[i];
#pragma unroll
      for (int ni = 0; ni < 4; ni++)
#pragma unroll
        for (int i = 0; i < 4; i++)
          Pw[(fg * 4 + i) * 72 + ni * 16 + fr] = f2bf(sa[ni][i]);
      // PV: O += P @ V (wave-private P, swizzled V reads)
      __builtin_amdgcn_s_setprio(1);
#pragma unroll
      for (int k2 = 0; k2 < 2; k2++) {
        bf16x8 pf = *(const bf16x8*)&Pw[fr * 72 + k2 * 32 + fg * 8];
#pragma unroll
        for (int ni = 0; ni < 8; ni++) {
          bf16x8 vf = *(const bf16x8*)&Vb[cur][(ni * 16 + fr) * 64 + (((k2 * 4 + fg) ^ frs) * 8)];
          acc[ni] = __builtin_amdgcn_mfma_f32_16x16x32_bf16(pf, vf, acc[ni], 0, 0, 0);
        }
      }
      __builtin_amdgcn_s_setprio(0);
      __syncthreads();                             // next tile staged; K/V reads done
      cur ^= 1;
    }
    // epilogue: attn_bf[((b*S+s)*NH+h)*HD + d]
#pragma unroll
    for (int i = 0; i < 4; i++) {
      int s = q0 + w * 16 + fg * 4 + i;
      float inv = 1.f / l[i];
#pragma unroll
      for (int ni = 0; ni < 8; ni++)
        aout[(((size_t)b * 1024 + s) * 16 + h) * 128 + ni * 16 + fr] = f2bf(acc[ni][i] * inv);
    }
    if (pass == 0) __syncthreads();                // buffers reused next pass
  }
}

// ---------------- launcher ----------------
extern "C" void kernel_launch(void* const* d_in, const int* in_sizes, int n_in,
                              void* d_out, int out_size, void* d_ws, size_t ws_size,
                              hipStream_t stream) {
  const float* hs  = (const float*)d_in[0];
  const float* key = (const float*)d_in[1];
  const float* val = (const float*)d_in[2];
  // d_in[3]: attention_mask — causal, reproduced analytically
  const float* rc  = (const float*)d_in[4];
  const float* rs  = (const float*)d_in[5];
  const float* wq  = (const float*)d_in[6];
  const float* bq  = (const float*)d_in[7];
  const float* wo  = (const float*)d_in[8];
  const float* bo  = (const float*)d_in[9];
  float* out = (float*)d_out;

  char* ws = (char*)d_ws;
  u16* hs_bf = (u16*)(ws);                   // 16 MB ; reused as attn_bf
  u16* wq_bf = (u16*)(ws + 16777216);        //  8 MB
  u16* wo_bf = (u16*)(ws + 25165824);        //  8 MB
  u16* q_bf  = (u16*)(ws + 33554432);        // 16 MB
  u16* kT    = (u16*)(ws + 50331648);        // 16 MB  [bh][s][d]
  u16* vT    = (u16*)(ws + 67108864);        // 16 MB  [bh][d][s]
  u16* attn_bf = hs_bf;                      // hs_bf dead after gemm_rope

  cvt_kernel<<<8192, 256, 0, stream>>>(hs, hs_bf, 8388608 / 4);
  cvt_kernel<<<4096, 256, 0, stream>>>(wq, wq_bf, 4194304 / 4);
  cvt_kernel<<<4096, 256, 0, stream>>>(wo, wo_bf, 4194304 / 4);

  transpose_cvt<<<dim3(64, 128), 256, 0, stream>>>(key, kT, 128, 1024);   // -> kT[bh][s][d]
  transpose_cvt<<<dim3(64, 128), 256, 0, stream>>>(val, vT, 1024, 128);   // -> vT[bh][d][s]

  gemm_rope<<<dim3(32, 16), 256, 0, stream>>>(hs_bf, wq_bf, bq, rc, rs, q_bf);
  attn_kernel<<<512, 256, 0, stream>>>(q_bf, kT, vT, attn_bf);
  gemm_bt<false><<<dim3(32, 16), 256, 0, stream>>>(attn_bf, wo_bf, bo, out, 4096, 2048, 2048);
}